// Round 5
// baseline (243.651 us; speedup 1.0000x reference)
//
#include <hip/hip_runtime.h>
#include <hip/hip_bf16.h>
#include <math.h>

#define HIDDEN 1024
#define ADIM 32
#define NEMB 32
#define BB 128
#define TT 16
#define NROWS (BB*TT)   // 2048
#define KSPLIT 4

#define OCT_STRIDE 136    // u16: 128 data + 8 pad
#define GN_STRIDE  1096   // u16: 8*136 + 8 pad
#define BS_U16     (16 * GN_STRIDE)   // 17536 u16 = 35072 B per buffer

typedef float f32x4 __attribute__((ext_vector_type(4)));
typedef short bf16x8 __attribute__((ext_vector_type(8)));
typedef unsigned short u16;

static __device__ __forceinline__ u16 f2bf(float f) {
    union { __hip_bfloat16 h; u16 u; } cv;
    cv.h = __float2bfloat16(f);   // RNE
    return cv.u;
}

// raw barrier: NO vmcnt drain (keep global loads in flight), but complete LDS ops.
#define BARRIER() do { \
    asm volatile("s_waitcnt lgkmcnt(0)" ::: "memory"); \
    __builtin_amdgcn_s_barrier(); \
    asm volatile("" ::: "memory"); \
} while (0)

// ws layout:
//  [0, 4096)   : meta ints: [0..31]=cnt, [32..63]=off, [64..191]=blist,
//                [192]=ntiles, [200+4i..]=tiles (row0, rows, e)
//  xg  @ 4096  : 2048 x 2048 bf16 (8MB), grouped rows
//  yg  @ +8MB  : 2048 x 1024 bf16 (4MB), grouped rows
//  pbuf @ +4MB : KSPLIT x 2048 x 1024 f32 (32MB)

__global__ void prep_kernel(const int* __restrict__ cat, int* __restrict__ meta) {
    __shared__ int c[BB];
    int tid = threadIdx.x;
    if (tid < BB) c[tid] = cat[tid];
    __syncthreads();
    if (tid == 0) {
        int cnt[NEMB];
        for (int e = 0; e < NEMB; e++) cnt[e] = 0;
        for (int b = 0; b < BB; b++) cnt[c[b]]++;
        int off = 0;
        for (int e = 0; e < NEMB; e++) { meta[e] = cnt[e]; meta[32 + e] = off; off += cnt[e]; }
        int pos[NEMB];
        for (int e = 0; e < NEMB; e++) pos[e] = meta[32 + e];
        for (int b = 0; b < BB; b++) { int e = c[b]; meta[64 + pos[e]] = b; pos[e]++; }
        int nt = 0;
        for (int e = 0; e < NEMB; e++) {
            int Me = cnt[e] * TT;
            int base = meta[32 + e] * TT;
            for (int mb = 0; mb * 64 < Me; mb++) {
                int rows = Me - mb * 64; if (rows > 64) rows = 64;
                meta[200 + 4 * nt + 0] = base + mb * 64;
                meta[200 + 4 * nt + 1] = rows;
                meta[200 + 4 * nt + 2] = e;
                nt++;
            }
        }
        meta[192] = nt;   // <= 56
    }
}

// Layer 1 + PE, written grouped as bf16.
__global__ __launch_bounds__(256) void build_x_kernel(
    const float* __restrict__ actions, const int* __restrict__ timesteps,
    const int* __restrict__ cat_ids, const float* __restrict__ W1,
    const float* __restrict__ b1, const int* __restrict__ meta,
    u16* __restrict__ xg)
{
    int sb = blockIdx.x;
    int b  = meta[64 + sb];
    int e  = cat_ids[b];
    int tid = threadIdx.x;

    __shared__ float act[TT][ADIM];
    for (int i = tid; i < TT * ADIM; i += 256)
        act[i / ADIM][i % ADIM] = actions[(size_t)b * TT * ADIM + i];
    __syncthreads();

    float tau = (float)timesteps[b];

    for (int h = tid; h < HIDDEN; h += 256) {
        float acc[TT];
        #pragma unroll
        for (int t = 0; t < TT; t++) acc[t] = 0.f;
        for (int d = 0; d < ADIM; d++) {
            float w = W1[((size_t)e * ADIM + d) * HIDDEN + h];
            #pragma unroll
            for (int t = 0; t < TT; t++) acc[t] += act[t][d] * w;
        }
        float bv = b1[(size_t)e * HIDDEN + h];
        for (int t = 0; t < TT; t++)
            xg[(size_t)(sb * TT + t) * 2048 + h] = f2bf(acc[t] + bv);
    }

    for (int j = tid; j < HIDDEN; j += 256) {
        int i = j >> 1;
        float arg = tau * expf((float)i * -0.017988946f);
        float v = (j & 1) ? cosf(arg) : sinf(arg);
        u16 bv = f2bf(v);
        for (int t = 0; t < TT; t++)
            xg[(size_t)(sb * TT + t) * 2048 + 1024 + j] = bv;
    }
}

// Streaming grouped GEMM, split-K partials.
// 1D grid: bid = kc + 4*nq + 16*slot. Tile 64m x 256n, BK=64, dbuf LDS,
// raw-barrier pipeline with 2-deep register prefetch of B (loads stay in
// flight across barriers; only dependency-counted vmcnt waits).
__global__ __launch_bounds__(512, 4) void gemm_stream(
    const u16* __restrict__ X,        // grouped rows bf16, ld = ldx
    const float* __restrict__ W,      // (NEMB, Kdim, 1024) f32
    float* __restrict__ pbuf,         // KSPLIT x 2048 x 1024 f32
    const int* __restrict__ meta,
    int Kdim, int ldx)
{
    int bid  = blockIdx.x;
    int kc   = bid & 3;
    int nq   = (bid >> 2) & 3;
    int slot = bid >> 4;
    if (slot >= meta[192]) return;
    int row0      = meta[200 + 4 * slot + 0];
    int rowsValid = meta[200 + 4 * slot + 1];
    int e         = meta[200 + 4 * slot + 2];

    int n0  = nq * 256;
    int KC  = Kdim / KSPLIT;
    int kc0 = kc * KC;
    int nT  = KC >> 6;          // K-steps of 64 (8 for K=2048, 4 for K=1024; even)

    __shared__ u16 Bs[2][BS_U16];

    int tid  = threadIdx.x;
    int lane = tid & 63;
    int wid  = tid >> 6;
    int wm   = wid & 1;     // m-half (32 rows)
    int wn   = wid >> 1;    // n-quarter (64 cols = 4 gn)

    const float* Wp = W + (size_t)e * Kdim * 1024 + n0;

    // B stage map: bn4 = n-quad (0..63), bo = k-octet (0..7); 8 rows f32x4 each.
    int bn4 = tid & 63;
    int bo  = tid >> 6;

    f32x4 bA[8], bB[8];     // 2-deep ping-pong prefetch
    f32x4 acc[2][4];
    #pragma unroll
    for (int mi = 0; mi < 2; mi++)
        #pragma unroll
        for (int g = 0; g < 4; g++)
            acc[mi][g] = (f32x4){0.f, 0.f, 0.f, 0.f};

    #define LOADB(reg, kt) do { \
        int kb = kc0 + (kt) * 64 + bo * 8; \
        _Pragma("unroll") \
        for (int r = 0; r < 8; r++) \
            reg[r] = *(const f32x4*)&Wp[(size_t)(kb + r) * 1024 + bn4 * 4]; \
    } while (0)

    #define WRITEB(reg, c) do { \
        _Pragma("unroll") \
        for (int j = 0; j < 4; j++) { \
            int n = bn4 * 4 + j; \
            bf16x8 v; \
            _Pragma("unroll") \
            for (int r = 0; r < 8; r++) v[r] = (short)f2bf(reg[r][j]); \
            *(bf16x8*)&Bs[c][(n >> 4) * GN_STRIDE + bo * OCT_STRIDE + (n & 15) * 8] = v; \
        } \
    } while (0)

    #define COMPUTE(c, kt) do { \
        int kg = kc0 + (kt) * 64; \
        _Pragma("unroll") \
        for (int h = 0; h < 2; h++) { \
            bf16x8 af[2]; \
            _Pragma("unroll") \
            for (int mi = 0; mi < 2; mi++) { \
                int m = wm * 32 + mi * 16 + (lane & 15); \
                af[mi] = *(const bf16x8*)&X[(size_t)(row0 + m) * ldx + kg + h * 32 + (lane >> 4) * 8]; \
            } \
            _Pragma("unroll") \
            for (int g = 0; g < 4; g++) { \
                int gn = wn * 4 + g; \
                bf16x8 bf = *(const bf16x8*)&Bs[c][gn * GN_STRIDE + (h * 4 + (lane >> 4)) * OCT_STRIDE + (lane & 15) * 8]; \
                _Pragma("unroll") \
                for (int mi = 0; mi < 2; mi++) \
                    acc[mi][g] = __builtin_amdgcn_mfma_f32_16x16x32_bf16(af[mi], bf, acc[mi][g], 0, 0, 0); \
            } \
        } \
    } while (0)

    LOADB(bA, 0);
    if (nT > 1) LOADB(bB, 1);

    for (int kt = 0; kt < nT; kt += 2) {
        // even step: regs bA, LDS buf 0
        WRITEB(bA, 0);                       // counted-vmcnt drains only bA's 8 loads
        if (kt + 2 < nT) LOADB(bA, kt + 2);  // stays in flight across raw barriers
        BARRIER();
        COMPUTE(0, kt);
        // odd step: regs bB, LDS buf 1
        WRITEB(bB, 1);
        if (kt + 3 < nT) LOADB(bB, kt + 3);
        BARRIER();
        COMPUTE(1, kt + 1);
    }

    // partial store (row-major pbuf)
    float* pb = pbuf + (size_t)kc * NROWS * 1024;
    int col = n0 + wn * 64 + (lane & 15);
    #pragma unroll
    for (int mi = 0; mi < 2; mi++) {
        #pragma unroll
        for (int r = 0; r < 4; r++) {
            int m = wm * 32 + mi * 16 + ((lane >> 4) << 2) + r;
            if (m < rowsValid) {
                float* dst = pb + (size_t)(row0 + m) * 1024 + col;
                #pragma unroll
                for (int g = 0; g < 4; g++)
                    dst[g * 16] = acc[mi][g][r];
            }
        }
    }
}

// yg = bf16(swish(sum_kc pbuf + b2)), grouped rows
__global__ __launch_bounds__(256) void reduce_mid(
    const float* __restrict__ pbuf, const float* __restrict__ b2,
    const int* __restrict__ meta, const int* __restrict__ cat,
    u16* __restrict__ yg)
{
    int r = blockIdx.x;
    int e = cat[meta[64 + (r >> 4)]];
    int c = threadIdx.x * 4;
    f32x4 s = *(const f32x4*)&pbuf[(size_t)r * 1024 + c];
    #pragma unroll
    for (int kc = 1; kc < KSPLIT; kc++) {
        f32x4 t = *(const f32x4*)&pbuf[(size_t)kc * NROWS * 1024 + (size_t)r * 1024 + c];
        s = s + t;
    }
    f32x4 bb = *(const f32x4*)&b2[(size_t)e * 1024 + c];
    ushort4 o;
    float h0 = s[0] + bb[0]; o.x = f2bf(h0 / (1.f + expf(-h0)));
    float h1 = s[1] + bb[1]; o.y = f2bf(h1 / (1.f + expf(-h1)));
    float h2 = s[2] + bb[2]; o.z = f2bf(h2 / (1.f + expf(-h2)));
    float h3 = s[3] + bb[3]; o.w = f2bf(h3 / (1.f + expf(-h3)));
    *(ushort4*)&yg[(size_t)r * 1024 + c] = o;
}

// out[natural] = sum_kc pbuf + b3
__global__ __launch_bounds__(256) void reduce_out(
    const float* __restrict__ pbuf, const float* __restrict__ b3,
    const int* __restrict__ meta, const int* __restrict__ cat,
    float* __restrict__ out)
{
    int r = blockIdx.x;
    int bnat = meta[64 + (r >> 4)];
    int e = cat[bnat];
    int c = threadIdx.x * 4;
    f32x4 s = *(const f32x4*)&pbuf[(size_t)r * 1024 + c];
    #pragma unroll
    for (int kc = 1; kc < KSPLIT; kc++) {
        f32x4 t = *(const f32x4*)&pbuf[(size_t)kc * NROWS * 1024 + (size_t)r * 1024 + c];
        s = s + t;
    }
    f32x4 bb = *(const f32x4*)&b3[(size_t)e * 1024 + c];
    s = s + bb;
    *(f32x4*)&out[((size_t)bnat * TT + (r & 15)) * 1024 + c] = s;
}

extern "C" void kernel_launch(void* const* d_in, const int* in_sizes, int n_in,
                              void* d_out, int out_size, void* d_ws, size_t ws_size,
                              hipStream_t stream) {
    const float* actions   = (const float*)d_in[0];
    const int*   timesteps = (const int*)d_in[1];
    const int*   cat_ids   = (const int*)d_in[2];
    const float* W1        = (const float*)d_in[3];
    const float* b1        = (const float*)d_in[4];
    const float* W2        = (const float*)d_in[5];
    const float* b2        = (const float*)d_in[6];
    const float* W3        = (const float*)d_in[7];
    const float* b3        = (const float*)d_in[8];
    float* out = (float*)d_out;

    int*  meta  = (int*)d_ws;
    u16*  xg    = (u16*)((char*)d_ws + 4096);
    u16*  yg    = (u16*)((char*)d_ws + 4096 + 8ull * 1024 * 1024);
    float* pbuf = (float*)((char*)d_ws + 4096 + 12ull * 1024 * 1024);

    prep_kernel<<<1, 128, 0, stream>>>(cat_ids, meta);
    build_x_kernel<<<128, 256, 0, stream>>>(actions, timesteps, cat_ids, W1, b1, meta, xg);

    // layer 2: K=2048
    gemm_stream<<<1024, 512, 0, stream>>>(xg, W2, pbuf, meta, 2048, 2048);
    reduce_mid<<<NROWS, 256, 0, stream>>>(pbuf, b2, meta, cat_ids, yg);

    // layer 3: K=1024
    gemm_stream<<<1024, 512, 0, stream>>>(yg, W3, pbuf, meta, 1024, 1024);
    reduce_out<<<NROWS, 256, 0, stream>>>(pbuf, b3, meta, cat_ids, out);
}

// Round 6
// 220.650 us; speedup vs baseline: 1.1042x; 1.1042x over previous
//
#include <hip/hip_runtime.h>
#include <hip/hip_bf16.h>
#include <math.h>

#define HIDDEN 1024
#define ADIM 32
#define NEMB 32
#define BB 128
#define TT 16
#define NROWS (BB*TT)   // 2048

// LDS B layout (BK=32): [gn:16][oct:4][n16:16 x bf16x8], u16 units
#define OCT_STRIDE 136                 // 128 data + 8 pad
#define GN_STRIDE  552                 // 4*136 + 8 pad
#define BS_U16     (16 * GN_STRIDE)    // 8832 u16 = 17664 B / buffer

typedef float f32x2 __attribute__((ext_vector_type(2)));
typedef float f32x4 __attribute__((ext_vector_type(4)));
typedef short bf16x8 __attribute__((ext_vector_type(8)));
typedef unsigned short u16;

static __device__ __forceinline__ u16 f2bf(float f) {
    union { __hip_bfloat16 h; u16 u; } cv;
    cv.h = __float2bfloat16(f);   // RNE
    return cv.u;
}

// raw barrier: completes LDS ops, leaves global loads in flight (no vmcnt drain)
#define BARRIER() do { \
    asm volatile("s_waitcnt lgkmcnt(0)" ::: "memory"); \
    __builtin_amdgcn_s_barrier(); \
    asm volatile("" ::: "memory"); \
} while (0)

// ws layout:
//  [0, 4096)   : meta ints: [0..31]=cnt, [32..63]=off, [64..191]=blist,
//                [192]=ntiles, [200+4i..]=tiles (row0, rows, e)
//  xg  @ 4096  : 2048 x 2048 bf16 (8MB), grouped rows
//  yg  @ +8MB  : 2048 x 1024 bf16 (4MB), grouped rows

__global__ void prep_kernel(const int* __restrict__ cat, int* __restrict__ meta) {
    __shared__ int c[BB];
    int tid = threadIdx.x;
    if (tid < BB) c[tid] = cat[tid];
    __syncthreads();
    if (tid == 0) {
        int cnt[NEMB];
        for (int e = 0; e < NEMB; e++) cnt[e] = 0;
        for (int b = 0; b < BB; b++) cnt[c[b]]++;
        int off = 0;
        for (int e = 0; e < NEMB; e++) { meta[e] = cnt[e]; meta[32 + e] = off; off += cnt[e]; }
        int pos[NEMB];
        for (int e = 0; e < NEMB; e++) pos[e] = meta[32 + e];
        for (int b = 0; b < BB; b++) { int e = c[b]; meta[64 + pos[e]] = b; pos[e]++; }
        int nt = 0;
        for (int e = 0; e < NEMB; e++) {
            int Me = cnt[e] * TT;
            int base = meta[32 + e] * TT;
            for (int mb = 0; mb * 64 < Me; mb++) {
                int rows = Me - mb * 64; if (rows > 64) rows = 64;
                meta[200 + 4 * nt + 0] = base + mb * 64;
                meta[200 + 4 * nt + 1] = rows;
                meta[200 + 4 * nt + 2] = e;
                nt++;
            }
        }
        meta[192] = nt;   // <= 56 (sum ceil(cnt/4) bound)
    }
}

// Layer 1 + PE, written grouped as bf16.
__global__ __launch_bounds__(256) void build_x_kernel(
    const float* __restrict__ actions, const int* __restrict__ timesteps,
    const int* __restrict__ cat_ids, const float* __restrict__ W1,
    const float* __restrict__ b1, const int* __restrict__ meta,
    u16* __restrict__ xg)
{
    int sb = blockIdx.x;
    int b  = meta[64 + sb];
    int e  = cat_ids[b];
    int tid = threadIdx.x;

    __shared__ float act[TT][ADIM];
    for (int i = tid; i < TT * ADIM; i += 256)
        act[i / ADIM][i % ADIM] = actions[(size_t)b * TT * ADIM + i];
    __syncthreads();

    float tau = (float)timesteps[b];

    for (int h = tid; h < HIDDEN; h += 256) {
        float acc[TT];
        #pragma unroll
        for (int t = 0; t < TT; t++) acc[t] = 0.f;
        for (int d = 0; d < ADIM; d++) {
            float w = W1[((size_t)e * ADIM + d) * HIDDEN + h];
            #pragma unroll
            for (int t = 0; t < TT; t++) acc[t] += act[t][d] * w;
        }
        float bv = b1[(size_t)e * HIDDEN + h];
        for (int t = 0; t < TT; t++)
            xg[(size_t)(sb * TT + t) * 2048 + h] = f2bf(acc[t] + bv);
    }

    for (int j = tid; j < HIDDEN; j += 256) {
        int i = j >> 1;
        float arg = tau * expf((float)i * -0.017988946f);
        float v = (j & 1) ? cosf(arg) : sinf(arg);
        u16 bv = f2bf(v);
        for (int t = 0; t < TT; t++)
            xg[(size_t)(sb * TT + t) * 2048 + 1024 + j] = bv;
    }
}

// Fused streaming grouped GEMM (no split-K).
// grid 1D: bid = nq + 4*slot (<=224 live). Tile 64m x 256n, BK=32.
// 8 waves (2m x 4n). Double-buffered LDS for B, 2-deep B reg prefetch
// (8 x f32x2 each), A (bf16, from global/L2) ping-pong one phase ahead.
// Raw lgkm-only barriers keep the B stream in flight across phases.
// mode 0: +bias, swish, bf16 store to grouped rows. mode 1: +bias, f32
// store scattered to natural (b,t) order.
__global__ __launch_bounds__(512, 4) void gemm_fused(
    const u16* __restrict__ X,        // grouped rows bf16, ld = ldx
    const float* __restrict__ W,      // (NEMB, Kdim, 1024) f32
    const float* __restrict__ bias,   // (NEMB, 1024) f32
    void* __restrict__ outp,
    const int* __restrict__ meta,
    int Kdim, int ldx, int mode)
{
    int bid  = blockIdx.x;
    int nq   = bid & 3;
    int slot = bid >> 2;
    if (slot >= meta[192]) return;
    int row0      = meta[200 + 4 * slot + 0];
    int rowsValid = meta[200 + 4 * slot + 1];
    int e         = meta[200 + 4 * slot + 2];

    int n0 = nq * 256;
    int nT = Kdim >> 5;            // K-steps of 32 (32 or 64; even)

    __shared__ u16 Bs[2][BS_U16];

    int tid  = threadIdx.x;
    int lane = tid & 63;
    int wid  = tid >> 6;
    int wm   = wid & 1;            // m-half (32 rows)
    int wn   = wid >> 1;           // n-quarter (64 cols)

    const float* Wp = W + (size_t)e * Kdim * 1024 + n0;

    // B stage map: np = n-pair (0..127), ko = k-octet (0..3); 8 rows f32x2 each
    int np = tid & 127;
    int ko = tid >> 7;

    f32x2  b0[8], b1[8];           // 2-deep ping-pong (16 VGPR each)
    bf16x8 a0[2], a1[2];           // A ping-pong, one phase ahead

    f32x4 acc[2][4];
    #pragma unroll
    for (int mi = 0; mi < 2; mi++)
        #pragma unroll
        for (int g = 0; g < 4; g++)
            acc[mi][g] = (f32x4){0.f, 0.f, 0.f, 0.f};

    #define LOADB(reg, kt) do { \
        _Pragma("unroll") \
        for (int r = 0; r < 8; r++) \
            reg[r] = *(const f32x2*)&Wp[(size_t)((kt) * 32 + ko * 8 + r) * 1024 + np * 2]; \
    } while (0)

    #define LOADA(reg, kt) do { \
        _Pragma("unroll") \
        for (int mi = 0; mi < 2; mi++) { \
            int m = wm * 32 + mi * 16 + (lane & 15); \
            reg[mi] = *(const bf16x8*)&X[(size_t)(row0 + m) * ldx + (kt) * 32 + (lane >> 4) * 8]; \
        } \
    } while (0)

    #define WRITEB(reg, c) do { \
        _Pragma("unroll") \
        for (int j = 0; j < 2; j++) { \
            int n = np * 2 + j; \
            bf16x8 v; \
            _Pragma("unroll") \
            for (int r = 0; r < 8; r++) v[r] = (short)f2bf(reg[r][j]); \
            *(bf16x8*)&Bs[c][(n >> 4) * GN_STRIDE + ko * OCT_STRIDE + (n & 15) * 8] = v; \
        } \
    } while (0)

    #define COMPUTE(c, aP) do { \
        _Pragma("unroll") \
        for (int g = 0; g < 4; g++) { \
            int gn = wn * 4 + g; \
            bf16x8 bf = *(const bf16x8*)&Bs[c][gn * GN_STRIDE + (lane >> 4) * OCT_STRIDE + (lane & 15) * 8]; \
            _Pragma("unroll") \
            for (int mi = 0; mi < 2; mi++) \
                acc[mi][g] = __builtin_amdgcn_mfma_f32_16x16x32_bf16(aP[mi], bf, acc[mi][g], 0, 0, 0); \
        } \
    } while (0)

    // prologue: B(0), A(0), B(1) -- issue order matters for vmcnt counting
    LOADB(b0, 0);
    LOADA(a0, 0);
    LOADB(b1, 1);

    for (int kt = 0; kt < nT; kt += 2) {
        // phase A: compute kt from lds0 (b0 regs -> lds0)
        WRITEB(b0, 0);                        // waits only b0's loads (b1 stays in flight)
        if (kt + 1 < nT) LOADA(a1, kt + 1);
        if (kt + 2 < nT) LOADB(b0, kt + 2);
        BARRIER();
        COMPUTE(0, a0);
        // phase B: compute kt+1 from lds1
        WRITEB(b1, 1);                        // waits only b1's loads
        if (kt + 2 < nT) LOADA(a0, kt + 2);
        if (kt + 3 < nT) LOADB(b1, kt + 3);
        BARRIER();
        COMPUTE(1, a1);
    }

    // fused epilogue
    int col = n0 + wn * 64 + (lane & 15);
    float bv[4];
    #pragma unroll
    for (int g = 0; g < 4; g++) bv[g] = bias[(size_t)e * 1024 + col + g * 16];

    #pragma unroll
    for (int mi = 0; mi < 2; mi++) {
        #pragma unroll
        for (int r = 0; r < 4; r++) {
            int m = wm * 32 + mi * 16 + ((lane >> 4) << 2) + r;
            if (m < rowsValid) {
                int grow = row0 + m;
                if (mode == 0) {
                    u16* dst = (u16*)outp + (size_t)grow * 1024 + col;
                    #pragma unroll
                    for (int g = 0; g < 4; g++) {
                        float h = acc[mi][g][r] + bv[g];
                        h = h / (1.f + expf(-h));
                        dst[g * 16] = f2bf(h);
                    }
                } else {
                    int bnat = meta[64 + (grow >> 4)];
                    float* dst = (float*)outp + ((size_t)bnat * TT + (grow & 15)) * 1024 + col;
                    #pragma unroll
                    for (int g = 0; g < 4; g++)
                        dst[g * 16] = acc[mi][g][r] + bv[g];
                }
            }
        }
    }

    #undef LOADB
    #undef LOADA
    #undef WRITEB
    #undef COMPUTE
}

extern "C" void kernel_launch(void* const* d_in, const int* in_sizes, int n_in,
                              void* d_out, int out_size, void* d_ws, size_t ws_size,
                              hipStream_t stream) {
    const float* actions   = (const float*)d_in[0];
    const int*   timesteps = (const int*)d_in[1];
    const int*   cat_ids   = (const int*)d_in[2];
    const float* W1        = (const float*)d_in[3];
    const float* b1        = (const float*)d_in[4];
    const float* W2        = (const float*)d_in[5];
    const float* b2        = (const float*)d_in[6];
    const float* W3        = (const float*)d_in[7];
    const float* b3        = (const float*)d_in[8];
    float* out = (float*)d_out;

    int* meta = (int*)d_ws;
    u16* xg   = (u16*)((char*)d_ws + 4096);
    u16* yg   = (u16*)((char*)d_ws + 4096 + 8ull * 1024 * 1024);

    prep_kernel<<<1, 128, 0, stream>>>(cat_ids, meta);
    build_x_kernel<<<128, 256, 0, stream>>>(actions, timesteps, cat_ids, W1, b1, meta, xg);

    // layer 2: K=2048, swish, bf16 grouped -> yg
    gemm_fused<<<224, 512, 0, stream>>>(xg, W2, b2, (void*)yg, meta, 2048, 2048, 0);
    // layer 3: K=1024, +bias, f32 natural scatter -> out
    gemm_fused<<<224, 512, 0, stream>>>(yg, W3, b3, (void*)out, meta, 1024, 1024, 1);
}

// Round 7
// 220.389 us; speedup vs baseline: 1.1056x; 1.0012x over previous
//
#include <hip/hip_runtime.h>
#include <hip/hip_bf16.h>
#include <math.h>

#define HIDDEN 1024
#define ADIM 32
#define NEMB 32
#define BB 128
#define TT 16
#define NROWS (BB*TT)   // 2048

// LDS B layout (BK=64, BN=64): [gn:4][oct:8][n16:16 x bf16x8], u16 units
#define OCT_STRIDE 136                 // 128 data + 8 pad
#define GN_STRIDE  1096                // 8*136 + 8 pad
#define BS_U16     (4 * GN_STRIDE)     // 4384 u16 = 8768 B / buffer

typedef float f32x2 __attribute__((ext_vector_type(2)));
typedef float f32x4 __attribute__((ext_vector_type(4)));
typedef short bf16x8 __attribute__((ext_vector_type(8)));
typedef unsigned short u16;

static __device__ __forceinline__ u16 f2bf(float f) {
    union { __hip_bfloat16 h; u16 u; } cv;
    cv.h = __float2bfloat16(f);   // RNE
    return cv.u;
}

// raw barrier: completes LDS ops, leaves global loads in flight (no vmcnt drain)
#define BARRIER() do { \
    asm volatile("s_waitcnt lgkmcnt(0)" ::: "memory"); \
    __builtin_amdgcn_s_barrier(); \
    asm volatile("" ::: "memory"); \
} while (0)

// ws layout:
//  [0, 4096)   : meta ints: [0..31]=cnt, [32..63]=off, [64..191]=blist,
//                [192]=ntiles, [200+4i..]=tiles (row0, rows, e)
//  xg  @ 4096  : 2048 x 2048 bf16 (8MB), grouped rows
//  yg  @ +8MB  : 2048 x 1024 bf16 (4MB), grouped rows

__global__ void prep_kernel(const int* __restrict__ cat, int* __restrict__ meta) {
    __shared__ int c[BB];
    int tid = threadIdx.x;
    if (tid < BB) c[tid] = cat[tid];
    __syncthreads();
    if (tid == 0) {
        int cnt[NEMB];
        for (int e = 0; e < NEMB; e++) cnt[e] = 0;
        for (int b = 0; b < BB; b++) cnt[c[b]]++;
        int off = 0;
        for (int e = 0; e < NEMB; e++) { meta[e] = cnt[e]; meta[32 + e] = off; off += cnt[e]; }
        int pos[NEMB];
        for (int e = 0; e < NEMB; e++) pos[e] = meta[32 + e];
        for (int b = 0; b < BB; b++) { int e = c[b]; meta[64 + pos[e]] = b; pos[e]++; }
        int nt = 0;
        for (int e = 0; e < NEMB; e++) {
            int Me = cnt[e] * TT;
            int base = meta[32 + e] * TT;
            for (int mb = 0; mb * 64 < Me; mb++) {
                int rows = Me - mb * 64; if (rows > 64) rows = 64;
                meta[200 + 4 * nt + 0] = base + mb * 64;
                meta[200 + 4 * nt + 1] = rows;
                meta[200 + 4 * nt + 2] = e;
                nt++;
            }
        }
        meta[192] = nt;   // <= 56
    }
}

// Layer 1 + PE, written grouped as bf16.
__global__ __launch_bounds__(256) void build_x_kernel(
    const float* __restrict__ actions, const int* __restrict__ timesteps,
    const int* __restrict__ cat_ids, const float* __restrict__ W1,
    const float* __restrict__ b1, const int* __restrict__ meta,
    u16* __restrict__ xg)
{
    int sb = blockIdx.x;
    int b  = meta[64 + sb];
    int e  = cat_ids[b];
    int tid = threadIdx.x;

    __shared__ float act[TT][ADIM];
    for (int i = tid; i < TT * ADIM; i += 256)
        act[i / ADIM][i % ADIM] = actions[(size_t)b * TT * ADIM + i];
    __syncthreads();

    float tau = (float)timesteps[b];

    for (int h = tid; h < HIDDEN; h += 256) {
        float acc[TT];
        #pragma unroll
        for (int t = 0; t < TT; t++) acc[t] = 0.f;
        for (int d = 0; d < ADIM; d++) {
            float w = W1[((size_t)e * ADIM + d) * HIDDEN + h];
            #pragma unroll
            for (int t = 0; t < TT; t++) acc[t] += act[t][d] * w;
        }
        float bv = b1[(size_t)e * HIDDEN + h];
        for (int t = 0; t < TT; t++)
            xg[(size_t)(sb * TT + t) * 2048 + h] = f2bf(acc[t] + bv);
    }

    for (int j = tid; j < HIDDEN; j += 256) {
        int i = j >> 1;
        float arg = tau * expf((float)i * -0.017988946f);
        float v = (j & 1) ? cosf(arg) : sinf(arg);
        u16 bv = f2bf(v);
        for (int t = 0; t < TT; t++)
            xg[(size_t)(sb * TT + t) * 2048 + 1024 + j] = bv;
    }
}

// Fused streaming grouped GEMM.
// grid 1D: bid = nq(16) + 16*slot  -> up to 896 live blocks (~3/CU).
// Tile 64m x 64n, BK=64. 256 threads (4 waves: 2m x 2n).
// Double-buffered LDS for B, 2-deep B reg ping-pong (8 x f32x2 each),
// A (bf16 from global/L2) ping-pong one phase ahead. Raw lgkm-only
// barriers; every vmcnt wait is dependency-counted, B stream never drains.
// mode 0: +bias, swish, bf16 store grouped. mode 1: +bias, f32 natural scatter.
__global__ __launch_bounds__(256, 3) void gemm_fused(
    const u16* __restrict__ X,        // grouped rows bf16, ld = ldx
    const float* __restrict__ W,      // (NEMB, Kdim, 1024) f32
    const float* __restrict__ bias,   // (NEMB, 1024) f32
    void* __restrict__ outp,
    const int* __restrict__ meta,
    int Kdim, int ldx, int mode)
{
    int bid  = blockIdx.x;
    int nq   = bid & 15;
    int slot = bid >> 4;
    if (slot >= meta[192]) return;
    int row0      = meta[200 + 4 * slot + 0];
    int rowsValid = meta[200 + 4 * slot + 1];
    int e         = meta[200 + 4 * slot + 2];

    int n0 = nq * 64;
    int nT = Kdim >> 6;            // K-steps of 64 (32 or 16; even)

    __shared__ u16 Bs[2][BS_U16];

    int tid  = threadIdx.x;
    int lane = tid & 63;
    int wid  = tid >> 6;
    int wm   = wid & 1;            // m-half (32 rows)
    int wn   = wid >> 1;           // n-half (32 cols = 2 n16-groups)

    const float* Wp = W + (size_t)e * Kdim * 1024 + n0;

    // B stage map: np = n-pair (0..31), ko = k-octet (0..7); 8 rows f32x2 each
    int np = tid & 31;
    int ko = tid >> 5;

    f32x2  b0[8], b1[8];           // 2-deep ping-pong (16 VGPR each)
    bf16x8 a0[4], a1[4];           // A frags [h*2+mi], one phase ahead

    f32x4 acc[2][2];
    #pragma unroll
    for (int mi = 0; mi < 2; mi++)
        #pragma unroll
        for (int nj = 0; nj < 2; nj++)
            acc[mi][nj] = (f32x4){0.f, 0.f, 0.f, 0.f};

    #define LOADB(reg, kt) do { \
        _Pragma("unroll") \
        for (int r = 0; r < 8; r++) \
            reg[r] = *(const f32x2*)&Wp[(size_t)((kt) * 64 + ko * 8 + r) * 1024 + np * 2]; \
    } while (0)

    #define LOADA(reg, kt) do { \
        _Pragma("unroll") \
        for (int h = 0; h < 2; h++) \
            _Pragma("unroll") \
            for (int mi = 0; mi < 2; mi++) { \
                int m = wm * 32 + mi * 16 + (lane & 15); \
                reg[h * 2 + mi] = *(const bf16x8*)&X[(size_t)(row0 + m) * ldx + (kt) * 64 + h * 32 + (lane >> 4) * 8]; \
            } \
    } while (0)

    #define WRITEB(reg, c) do { \
        _Pragma("unroll") \
        for (int j = 0; j < 2; j++) { \
            int n = np * 2 + j; \
            bf16x8 v; \
            _Pragma("unroll") \
            for (int r = 0; r < 8; r++) v[r] = (short)f2bf(reg[r][j]); \
            *(bf16x8*)&Bs[c][(n >> 4) * GN_STRIDE + ko * OCT_STRIDE + (n & 15) * 8] = v; \
        } \
    } while (0)

    #define COMPUTE(c, aP) do { \
        _Pragma("unroll") \
        for (int h = 0; h < 2; h++) \
            _Pragma("unroll") \
            for (int nj = 0; nj < 2; nj++) { \
                int gn = wn * 2 + nj; \
                bf16x8 bf = *(const bf16x8*)&Bs[c][gn * GN_STRIDE + (h * 4 + (lane >> 4)) * OCT_STRIDE + (lane & 15) * 8]; \
                _Pragma("unroll") \
                for (int mi = 0; mi < 2; mi++) \
                    acc[mi][nj] = __builtin_amdgcn_mfma_f32_16x16x32_bf16(aP[h * 2 + mi], bf, acc[mi][nj], 0, 0, 0); \
            } \
    } while (0)

    // prologue (issue order defines vmcnt FIFO)
    LOADB(b0, 0);
    LOADA(a0, 0);
    LOADB(b1, 1);

    for (int kt = 0; kt < nT; kt += 2) {
        // phase A: compute kt from lds0
        WRITEB(b0, 0);                        // waits only b0's 8 loads
        if (kt + 1 < nT) LOADA(a1, kt + 1);
        if (kt + 2 < nT) LOADB(b0, kt + 2);
        BARRIER();
        COMPUTE(0, a0);
        // phase B: compute kt+1 from lds1
        WRITEB(b1, 1);                        // waits only b1's 8 loads
        if (kt + 2 < nT) LOADA(a0, kt + 2);
        if (kt + 3 < nT) LOADB(b1, kt + 3);
        BARRIER();
        COMPUTE(1, a1);
    }

    // fused epilogue
    float bv[2];
    #pragma unroll
    for (int nj = 0; nj < 2; nj++)
        bv[nj] = bias[(size_t)e * 1024 + n0 + wn * 32 + nj * 16 + (lane & 15)];

    #pragma unroll
    for (int mi = 0; mi < 2; mi++) {
        #pragma unroll
        for (int r = 0; r < 4; r++) {
            int m = wm * 32 + mi * 16 + ((lane >> 4) << 2) + r;
            if (m < rowsValid) {
                int grow = row0 + m;
                int col = n0 + wn * 32 + (lane & 15);
                if (mode == 0) {
                    u16* dst = (u16*)outp + (size_t)grow * 1024 + col;
                    #pragma unroll
                    for (int nj = 0; nj < 2; nj++) {
                        float h = acc[mi][nj][r] + bv[nj];
                        h = h / (1.f + expf(-h));
                        dst[nj * 16] = f2bf(h);
                    }
                } else {
                    int bnat = meta[64 + (grow >> 4)];
                    float* dst = (float*)outp + ((size_t)bnat * TT + (grow & 15)) * 1024 + col;
                    #pragma unroll
                    for (int nj = 0; nj < 2; nj++)
                        dst[nj * 16] = acc[mi][nj][r] + bv[nj];
                }
            }
        }
    }

    #undef LOADB
    #undef LOADA
    #undef WRITEB
    #undef COMPUTE
}

extern "C" void kernel_launch(void* const* d_in, const int* in_sizes, int n_in,
                              void* d_out, int out_size, void* d_ws, size_t ws_size,
                              hipStream_t stream) {
    const float* actions   = (const float*)d_in[0];
    const int*   timesteps = (const int*)d_in[1];
    const int*   cat_ids   = (const int*)d_in[2];
    const float* W1        = (const float*)d_in[3];
    const float* b1        = (const float*)d_in[4];
    const float* W2        = (const float*)d_in[5];
    const float* b2        = (const float*)d_in[6];
    const float* W3        = (const float*)d_in[7];
    const float* b3        = (const float*)d_in[8];
    float* out = (float*)d_out;

    int* meta = (int*)d_ws;
    u16* xg   = (u16*)((char*)d_ws + 4096);
    u16* yg   = (u16*)((char*)d_ws + 4096 + 8ull * 1024 * 1024);

    prep_kernel<<<1, 128, 0, stream>>>(cat_ids, meta);
    build_x_kernel<<<128, 256, 0, stream>>>(actions, timesteps, cat_ids, W1, b1, meta, xg);

    // layer 2: K=2048, swish, bf16 grouped -> yg   (16 nq x <=56 slots)
    gemm_fused<<<896, 256, 0, stream>>>(xg, W2, b2, (void*)yg, meta, 2048, 2048, 0);
    // layer 3: K=1024, +bias, f32 natural scatter -> out
    gemm_fused<<<896, 256, 0, stream>>>(yg, W3, b3, (void*)out, meta, 1024, 1024, 1);
}